// Round 16
// baseline (176.608 us; speedup 1.0000x reference)
//
#include <hip/hip_runtime.h>
#include <hip/hip_bf16.h>
#include <math.h>

typedef float f32x4 __attribute__((ext_vector_type(4)));
typedef short bf16x8 __attribute__((ext_vector_type(8)));
typedef short bf16x4 __attribute__((ext_vector_type(4)));

#define AS1 __attribute__((address_space(1)))
#define AS3 __attribute__((address_space(3)))

__device__ __forceinline__ short f2bf(float f) {
    unsigned u = __float_as_uint(f);
    unsigned r = (u + 0x7fffu + ((u >> 16) & 1u)) >> 16;
    return (short)r;
}
__device__ __forceinline__ float bf2f(short s) {
    return __uint_as_float(((unsigned)(unsigned short)s) << 16);
}
__device__ __forceinline__ void gld16(const void* g, void* l) {
    __builtin_amdgcn_global_load_lds((const AS1 unsigned int*)g, (AS3 unsigned int*)l, 16, 0, 0);
}

// stage a [128][64]-short tile (global row stride 256 shorts) into linear LDS
// with XOR-swizzled SOURCE (slot ^= row&7); reads use the matching swizzle.
__device__ __forceinline__ void stage128x64(const short* __restrict__ g,
                                            short* lds, int t) {
    int w = t >> 6, l = t & 63;
    #pragma unroll
    for (int j = 0; j < 4; ++j) {
        int ii = j * 4 + w;
        int row = ii * 8 + (l >> 3);
        int slot = (l & 7) ^ (row & 7);
        gld16(g + row * 256 + slot * 8, lds + ii * 512);
    }
}

// ---------------- kernel 0+1 merged: weight transpose (bid<768) + pe/x transpose
__global__ __launch_bounds__(256) void k_prep(const float* __restrict__ x,
                                              const float* __restrict__ Wq,
                                              const float* __restrict__ Wk,
                                              const float* __restrict__ Wv,
                                              short* __restrict__ xt,
                                              short* __restrict__ Wt) {
    int bidx = blockIdx.x;              // 1280 = 768 wt + 512 pe
    if (bidx < 768) {
        int wsel = bidx >> 8, n = bidx & 255, k = threadIdx.x;
        const float* W = (wsel == 0) ? Wq : (wsel == 1) ? Wk : Wv;
        Wt[(wsel * 256 + n) * 256 + k] = f2bf(W[k * 256 + n]);
        return;
    }
    int bid = bidx - 768;               // 512 = 4 b * 128 pblocks(32)
    int b = bid >> 7;
    int pb = bid & 127;
    __shared__ __align__(16) float tile[256][33];
    __shared__ __align__(16) float pew[128][32];
    __shared__ __align__(16) float peh[128];
    int t = threadIdx.x;
    const float c1 = 0.14391156f;       // ln(10000)/64
    int wbase = (pb & 1) * 32;
    int hpos = pb >> 1;
    #pragma unroll
    for (int j = 0; j < 16; ++j) {
        int idx = t + j * 256;          // < 4096
        int c = idx >> 5, pp = idx & 31;
        int i = c >> 1;
        float d = expf(-(float)i * c1);
        float arg = (float)(wbase + pp) * d;
        pew[c][pp] = (c & 1) ? cosf(arg) : sinf(arg);
    }
    if (t < 128) {
        int i = t >> 1;
        float d = expf(-(float)i * c1);
        float arg = (float)hpos * d;
        peh[t] = (t & 1) ? cosf(arg) : sinf(arg);
    }
    int p0 = pb * 32;
    #pragma unroll
    for (int j = 0; j < 32; ++j) {
        int c = j * 8 + (t >> 5);
        int pp = t & 31;
        tile[c][pp] = x[((b * 256 + c) << 12) + p0 + pp];
    }
    __syncthreads();
    int pp = t >> 3, cseg = t & 7;
    int p = p0 + pp;
    short* dst = xt + (((b << 12) + p) << 8) + (cseg << 5);
    #pragma unroll
    for (int j = 0; j < 4; ++j) {
        bf16x8 v;
        #pragma unroll
        for (int e = 0; e < 8; ++e) {
            int c = cseg * 32 + j * 8 + e;
            float pe = (c < 128) ? pew[c][pp] : peh[c - 128];
            v[e] = f2bf(tile[c][pp] + pe);
        }
        ((bf16x8*)dst)[j] = v;
    }
}

// ---------------- kernel 2: LDS-staged projections (m97-style K-loop).
// Q = (xt@Wq)*0.0625, K = xt@Wk, V^T.
__global__ __launch_bounds__(256, 4) void k_proj(const short* __restrict__ xt,
                                                 const short* __restrict__ Wt,
                                                 short* __restrict__ Q,
                                                 short* __restrict__ K,
                                                 short* __restrict__ VT) {
    int id = blockIdx.x;                // 768 = 4b * 32mt * 2nt * 3w
    int wsel = id % 3; id /= 3;
    int nt = id & 1;  id >>= 1;
    int mt = id & 31; int b = id >> 5;
    int t = threadIdx.x, l = t & 63, w = t >> 6;
    int lr = l & 15, lg = l >> 4;
    int wr = w >> 1, wc = w & 1;        // wave sub-tile: 64m x 64n
    __shared__ __align__(16) short Xa[128 * 64];
    __shared__ __align__(16) short Wa[128 * 64];
    const short* Xg = xt + (((size_t)b << 12) + mt * 128) * 256;
    const short* Wg = Wt + ((size_t)wsel * 256 + nt * 128) * 256;
    f32x4 acc[4][4] = {};

    #pragma unroll
    for (int ks = 0; ks < 4; ++ks) {
        stage128x64(Xg + ks * 64, Xa, t);
        stage128x64(Wg + ks * 64, Wa, t);
        __syncthreads();
        #pragma unroll
        for (int s = 0; s < 2; ++s) {
            bf16x8 af[4], bw[4];
            #pragma unroll
            for (int ms = 0; ms < 4; ++ms) {
                int row = wr * 64 + ms * 16 + lr;
                af[ms] = *(const bf16x8*)(Xa + row * 64 + (((s * 4 + lg) ^ (row & 7)) << 3));
            }
            #pragma unroll
            for (int fn = 0; fn < 4; ++fn) {
                int row = wc * 64 + fn * 16 + lr;
                bw[fn] = *(const bf16x8*)(Wa + row * 64 + (((s * 4 + lg) ^ (row & 7)) << 3));
            }
            #pragma unroll
            for (int ms = 0; ms < 4; ++ms)
                #pragma unroll
                for (int fn = 0; fn < 4; ++fn)
                    acc[ms][fn] = __builtin_amdgcn_mfma_f32_16x16x32_bf16(af[ms], bw[fn], acc[ms][fn], 0, 0, 0);
        }
        __syncthreads();
    }

    int m0 = mt * 128 + wr * 64;
    int n0 = nt * 128 + wc * 64;
    if (wsel < 2) {
        float scl = (wsel == 0) ? 0.0625f : 1.0f;
        short* dst = (wsel == 0) ? Q : K;
        #pragma unroll
        for (int ms = 0; ms < 4; ++ms)
            #pragma unroll
            for (int fn = 0; fn < 4; ++fn)
                #pragma unroll
                for (int r = 0; r < 4; ++r) {
                    int m = m0 + ms * 16 + lg * 4 + r;
                    int n = n0 + fn * 16 + lr;
                    dst[((b << 12) + m) * 256 + n] = f2bf(acc[ms][fn][r] * scl);
                }
    } else {
        #pragma unroll
        for (int ms = 0; ms < 4; ++ms)
            #pragma unroll
            for (int fn = 0; fn < 4; ++fn) {
                int n = n0 + fn * 16 + lr;
                int m = m0 + ms * 16 + lg * 4;
                bf16x4 v;
                #pragma unroll
                for (int r = 0; r < 4; ++r) v[r] = f2bf(acc[ms][fn][r]);
                *(bf16x4*)(VT + ((b * 256 + n) << 12) + m) = v;
            }
    }
}

// ---------------- k_E: round-9 structure + __launch_bounds__(256,4) (round-12/13 proven)
__global__ __launch_bounds__(256, 4) void k_E(const short* __restrict__ Qm,
                                              const short* __restrict__ Km,
                                              short* __restrict__ E,
                                              float* __restrict__ pl) {
    int o = blockIdx.x;                 // 4096
    int bid = (o & 7) * 512 + (o >> 3); // XCD swizzle (4096 % 8 == 0)
    int qt = bid & 31, kt = (bid >> 5) & 31, b = bid >> 10;
    int t = threadIdx.x, l = t & 63;
    int w = t >> 6;
    int wr = w >> 1, wc = w & 1;        // wave sub-tile: 64k x 64q
    int lr = l & 15, lg = l >> 4;
    __shared__ __align__(16) short Ka[128 * 64];
    __shared__ __align__(16) short Qa[128 * 64];
    __shared__ float plds[128];
    const short* Kg = Km + (((size_t)b << 12) + kt * 128) * 256;
    const short* Qg = Qm + (((size_t)b << 12) + qt * 128) * 256;
    f32x4 acc[4][4] = {};

    #pragma unroll
    for (int ks = 0; ks < 4; ++ks) {
        stage128x64(Kg + ks * 64, Ka, t);
        stage128x64(Qg + ks * 64, Qa, t);
        __syncthreads();
        #pragma unroll
        for (int s = 0; s < 2; ++s) {
            bf16x8 a[4], bq[4];
            #pragma unroll
            for (int mk = 0; mk < 4; ++mk) {
                int row = wr * 64 + mk * 16 + lr;
                a[mk] = *(const bf16x8*)(Ka + row * 64 + (((s * 4 + lg) ^ (row & 7)) << 3));
            }
            #pragma unroll
            for (int nq = 0; nq < 4; ++nq) {
                int row = wc * 64 + nq * 16 + lr;
                bq[nq] = *(const bf16x8*)(Qa + row * 64 + (((s * 4 + lg) ^ (row & 7)) << 3));
            }
            #pragma unroll
            for (int mk = 0; mk < 4; ++mk)
                #pragma unroll
                for (int nq = 0; nq < 4; ++nq)
                    acc[mk][nq] = __builtin_amdgcn_mfma_f32_16x16x32_bf16(a[mk], bq[nq], acc[mk][nq], 0, 0, 0);
        }
        __syncthreads();
    }

    // epilogue: e = expf(acc) (scale pre-folded into Q), RNE pack, store,
    // and column (q) partial sums
    int k0 = kt * 128 + wr * 64;
    int q0 = qt * 128 + wc * 64;
    float psum[4][4];                   // [mk][r]
    #pragma unroll
    for (int mk = 0; mk < 4; ++mk) {
        float ps0 = 0.f, ps1 = 0.f, ps2 = 0.f, ps3 = 0.f;
        #pragma unroll
        for (int nq = 0; nq < 4; ++nq) {
            int q = q0 + nq * 16 + lr;
            float e0 = __expf(acc[mk][nq][0]);
            float e1 = __expf(acc[mk][nq][1]);
            float e2 = __expf(acc[mk][nq][2]);
            float e3 = __expf(acc[mk][nq][3]);
            ps0 += e0; ps1 += e1; ps2 += e2; ps3 += e3;
            bf16x4 ev;
            ev[0] = f2bf(e0); ev[1] = f2bf(e1); ev[2] = f2bf(e2); ev[3] = f2bf(e3);
            *(bf16x4*)(E + (((size_t)b << 12) + q) * 4096 + k0 + mk * 16 + lg * 4) = ev;
        }
        psum[mk][0] = ps0; psum[mk][1] = ps1; psum[mk][2] = ps2; psum[mk][3] = ps3;
    }
    #pragma unroll
    for (int mk = 0; mk < 4; ++mk)
        #pragma unroll
        for (int r = 0; r < 4; ++r) {
            float v = psum[mk][r];
            v += __shfl_xor(v, 1);
            v += __shfl_xor(v, 2);
            v += __shfl_xor(v, 4);
            v += __shfl_xor(v, 8);
            psum[mk][r] = v;
        }
    if (wc == 0 && lr == 0) {
        #pragma unroll
        for (int mk = 0; mk < 4; ++mk)
            #pragma unroll
            for (int r = 0; r < 4; ++r)
                plds[wr * 64 + mk * 16 + lg * 4 + r] = psum[mk][r];
    }
    __syncthreads();
    if (wc == 1 && lr == 0) {
        #pragma unroll
        for (int mk = 0; mk < 4; ++mk)
            #pragma unroll
            for (int r = 0; r < 4; ++r)
                plds[wr * 64 + mk * 16 + lg * 4 + r] += psum[mk][r];
    }
    __syncthreads();
    if (t < 128) pl[(b * 32 + qt) * 4096 + kt * 128 + t] = plds[t];
}

// k_lred: rl[b][k] = 1 / sum_qt pl[b][qt][k]
__global__ void k_lred(const float* __restrict__ pl, float* __restrict__ rl) {
    int gid = blockIdx.x * 256 + threadIdx.x;   // 16384
    float s = 0.f;
    int b = gid >> 12, k = gid & 4095;
    #pragma unroll
    for (int qt = 0; qt < 32; ++qt) s += pl[(b * 32 + qt) * 4096 + k];
    rl[gid] = 1.0f / s;
}

// k_vn: Vnt[b][c][k] = VT[b][c][k] * rl[b][k]
__global__ void k_vn(const short* __restrict__ VT, const float* __restrict__ rl,
                     short* __restrict__ Vnt) {
    int gid = blockIdx.x * 256 + threadIdx.x;   // 524288
    int idx8 = gid * 8;
    int b = idx8 >> 20;
    int rem = idx8 & 1048575;
    int k = rem & 4095;
    bf16x8 v = *(const bf16x8*)(VT + idx8);
    const float* rb = rl + (b << 12) + k;
    f32x4 r0 = *(const f32x4*)(rb);
    f32x4 r1 = *(const f32x4*)(rb + 4);
    bf16x8 oo;
    #pragma unroll
    for (int e = 0; e < 8; ++e) {
        float f = bf2f(v[e]);
        float rr = (e < 4) ? r0[e] : r1[e - 4];
        oo[e] = f2bf(f * rr);
    }
    *(bf16x8*)(Vnt + idx8) = oo;
}

// ---------------- k_pv v8: 64q x 256c block (ALL channels), 512 threads = 8 waves
// of 32q x 64c. E is read from HBM exactly ONCE by construction (no pairing
// heuristic). Single-buffered 40 KB LDS, 2 barriers/K-step. grid 256 (1 block/CU).
__global__ __launch_bounds__(512) void k_pv(const short* __restrict__ E,
                                            const short* __restrict__ Vnt,
                                            float* __restrict__ out) {
    int o = blockIdx.x;                 // 256
    int bid = (o & 7) * 32 + (o >> 3);  // XCD swizzle (256 % 8 == 0, bijective)
    int b = bid >> 6, qt = bid & 63;
    int t = threadIdx.x, l = t & 63, w = t >> 6;
    int wq = w >> 2, wc = w & 3;        // wave: 32 q x 64 c (2 x 4 waves)
    int lr = l & 15, lg = l >> 4;
    int q0 = qt * 64;
    __shared__ __align__(16) short Ea[64 * 64];    // 8 KB
    __shared__ __align__(16) short Va[256 * 64];   // 32 KB
    const short* Eg = E + (((size_t)b << 12) + q0) * 4096;
    const short* Vg = Vnt + ((size_t)b << 20);     // b * 256 * 4096
    f32x4 acc[2][4] = {};

    // per-thread staging coords (hoistable, ks-invariant)
    int erow = t >> 3, eslot = (t & 7) ^ ((t >> 3) & 7);   // E: 512 chunks, 1/thread
    for (int kc = 0; kc < 4096; kc += 64) {
        if (t < 512) {  // always true; keeps structure explicit
            gld16(Eg + kc + (size_t)erow * 4096 + eslot * 8, Ea + t * 8);
        }
        #pragma unroll
        for (int j = 0; j < 4; ++j) {   // V: 2048 chunks, 4/thread
            int idx = j * 512 + t;
            int row = idx >> 3;
            int slot = (idx & 7) ^ (row & 7);
            gld16(Vg + kc + (size_t)row * 4096 + slot * 8, Va + idx * 8);
        }
        __syncthreads();
        bf16x8 Af[2][2], Bf[4][2];
        #pragma unroll
        for (int s = 0; s < 2; ++s) {
            #pragma unroll
            for (int mq = 0; mq < 2; ++mq) {
                int row = wq * 32 + mq * 16 + lr;
                Af[mq][s] = *(const bf16x8*)(Ea + row * 64 + (((s * 4 + lg) ^ (row & 7)) << 3));
            }
            #pragma unroll
            for (int nc = 0; nc < 4; ++nc) {
                int row = wc * 64 + nc * 16 + lr;
                Bf[nc][s] = *(const bf16x8*)(Va + row * 64 + (((s * 4 + lg) ^ (row & 7)) << 3));
            }
        }
        #pragma unroll
        for (int s = 0; s < 2; ++s)
            #pragma unroll
            for (int mq = 0; mq < 2; ++mq)
                #pragma unroll
                for (int nc = 0; nc < 4; ++nc)
                    acc[mq][nc] = __builtin_amdgcn_mfma_f32_16x16x32_bf16(Af[mq][s], Bf[nc][s], acc[mq][nc], 0, 0, 0);
        __syncthreads();
    }
    #pragma unroll
    for (int mq = 0; mq < 2; ++mq)
        #pragma unroll
        for (int nc = 0; nc < 4; ++nc) {
            int c = wc * 64 + nc * 16 + lr;
            int q = q0 + wq * 32 + mq * 16 + lg * 4;
            *(f32x4*)(out + (((size_t)b << 8) + c) * 4096 + q) = acc[mq][nc];
        }
}

extern "C" void kernel_launch(void* const* d_in, const int* in_sizes, int n_in,
                              void* d_out, int out_size, void* d_ws, size_t ws_size,
                              hipStream_t stream) {
    const float* x  = (const float*)d_in[0];
    const float* Wq = (const float*)d_in[1];
    const float* Wk = (const float*)d_in[2];
    const float* Wv = (const float*)d_in[3];

    char* p = (char*)d_ws;
    short* xt  = (short*)p; p += 4 * 4096 * 256 * 2;   // 8 MB
    short* Wt  = (short*)p; p += 3 * 256 * 256 * 2;    // 384 KB
    short* Qm  = (short*)p; p += 4 * 4096 * 256 * 2;
    short* Km  = (short*)p; p += 4 * 4096 * 256 * 2;
    short* VT  = (short*)p; p += 4 * 4096 * 256 * 2;
    short* E   = (short*)p; p += (size_t)4 * 4096 * 4096 * 2;  // 134.2 MB
    float* pl  = (float*)p; p += 4 * 32 * 4096 * 4;            // 2 MB
    float* rl  = (float*)p; p += 4 * 4096 * 4;                 // 64 KB
    short* Vnt = (short*)p; p += 4 * 4096 * 256 * 2;           // 8 MB

    float* out = (float*)d_out;

    k_prep <<<1280, 256, 0, stream>>>(x, Wq, Wk, Wv, xt, Wt);
    k_proj <<<768, 256, 0, stream>>>(xt, Wt, Qm, Km, VT);
    k_E    <<<4096, 256, 0, stream>>>(Qm, Km, E, pl);
    k_lred <<<64,   256, 0, stream>>>(pl, rl);
    k_vn   <<<2048, 256, 0, stream>>>(VT, rl, Vnt);
    k_pv   <<<256,  512, 0, stream>>>(E, Vnt, out);
}

// Round 17
// 164.454 us; speedup vs baseline: 1.0739x; 1.0739x over previous
//
#include <hip/hip_runtime.h>
#include <hip/hip_bf16.h>
#include <math.h>

typedef float f32x4 __attribute__((ext_vector_type(4)));
typedef short bf16x8 __attribute__((ext_vector_type(8)));
typedef short bf16x4 __attribute__((ext_vector_type(4)));

#define AS1 __attribute__((address_space(1)))
#define AS3 __attribute__((address_space(3)))

__device__ __forceinline__ short f2bf(float f) {
    unsigned u = __float_as_uint(f);
    unsigned r = (u + 0x7fffu + ((u >> 16) & 1u)) >> 16;
    return (short)r;
}
__device__ __forceinline__ float bf2f(short s) {
    return __uint_as_float(((unsigned)(unsigned short)s) << 16);
}
__device__ __forceinline__ void gld16(const void* g, void* l) {
    __builtin_amdgcn_global_load_lds((const AS1 unsigned int*)g, (AS3 unsigned int*)l, 16, 0, 0);
}

// stage a [128][64]-short tile (global row stride 256 shorts) into linear LDS
// with XOR-swizzled SOURCE (slot ^= row&7); reads use the matching swizzle.
__device__ __forceinline__ void stage128x64(const short* __restrict__ g,
                                            short* lds, int t) {
    int w = t >> 6, l = t & 63;
    #pragma unroll
    for (int j = 0; j < 4; ++j) {
        int ii = j * 4 + w;
        int row = ii * 8 + (l >> 3);
        int slot = (l & 7) ^ (row & 7);
        gld16(g + row * 256 + slot * 8, lds + ii * 512);
    }
}

// stage a [64][64]-short tile (global row stride 4096) into linear LDS,
// source pre-swizzled with slot^=(row&7) (8 slots/row of 16B).
__device__ __forceinline__ void stage64x64(const short* __restrict__ g,
                                           short* lds, int t) {
    #pragma unroll
    for (int j = 0; j < 2; ++j) {
        int idx = j * 256 + t;
        int row = idx >> 3;
        int slot = (idx & 7) ^ (row & 7);
        gld16(g + (size_t)row * 4096 + slot * 8, lds + idx * 8);
    }
}

// stage a [128][64]-short tile (global row stride 4096) into linear LDS,
// source pre-swizzled with slot^=(row&7).
__device__ __forceinline__ void stage128x64v(const short* __restrict__ g,
                                             short* lds, int t) {
    #pragma unroll
    for (int j = 0; j < 4; ++j) {
        int idx = j * 256 + t;
        int row = idx >> 3;
        int slot = (idx & 7) ^ (row & 7);
        gld16(g + (size_t)row * 4096 + slot * 8, lds + idx * 8);
    }
}

// ---------------- kernel 0+1 merged: weight transpose (bid<768) + pe/x transpose
__global__ __launch_bounds__(256) void k_prep(const float* __restrict__ x,
                                              const float* __restrict__ Wq,
                                              const float* __restrict__ Wk,
                                              const float* __restrict__ Wv,
                                              short* __restrict__ xt,
                                              short* __restrict__ Wt) {
    int bidx = blockIdx.x;              // 1280 = 768 wt + 512 pe
    if (bidx < 768) {
        int wsel = bidx >> 8, n = bidx & 255, k = threadIdx.x;
        const float* W = (wsel == 0) ? Wq : (wsel == 1) ? Wk : Wv;
        Wt[(wsel * 256 + n) * 256 + k] = f2bf(W[k * 256 + n]);
        return;
    }
    int bid = bidx - 768;               // 512 = 4 b * 128 pblocks(32)
    int b = bid >> 7;
    int pb = bid & 127;
    __shared__ __align__(16) float tile[256][33];
    __shared__ __align__(16) float pew[128][32];
    __shared__ __align__(16) float peh[128];
    int t = threadIdx.x;
    const float c1 = 0.14391156f;       // ln(10000)/64
    int wbase = (pb & 1) * 32;
    int hpos = pb >> 1;
    #pragma unroll
    for (int j = 0; j < 16; ++j) {
        int idx = t + j * 256;          // < 4096
        int c = idx >> 5, pp = idx & 31;
        int i = c >> 1;
        float d = expf(-(float)i * c1);
        float arg = (float)(wbase + pp) * d;
        pew[c][pp] = (c & 1) ? cosf(arg) : sinf(arg);
    }
    if (t < 128) {
        int i = t >> 1;
        float d = expf(-(float)i * c1);
        float arg = (float)hpos * d;
        peh[t] = (t & 1) ? cosf(arg) : sinf(arg);
    }
    int p0 = pb * 32;
    #pragma unroll
    for (int j = 0; j < 32; ++j) {
        int c = j * 8 + (t >> 5);
        int pp = t & 31;
        tile[c][pp] = x[((b * 256 + c) << 12) + p0 + pp];
    }
    __syncthreads();
    int pp = t >> 3, cseg = t & 7;
    int p = p0 + pp;
    short* dst = xt + (((b << 12) + p) << 8) + (cseg << 5);
    #pragma unroll
    for (int j = 0; j < 4; ++j) {
        bf16x8 v;
        #pragma unroll
        for (int e = 0; e < 8; ++e) {
            int c = cseg * 32 + j * 8 + e;
            float pe = (c < 128) ? pew[c][pp] : peh[c - 128];
            v[e] = f2bf(tile[c][pp] + pe);
        }
        ((bf16x8*)dst)[j] = v;
    }
}

// ---------------- kernel 2: LDS-staged projections (m97-style K-loop).
// Q = (xt@Wq)*0.0625, K = xt@Wk, V^T.
__global__ __launch_bounds__(256, 4) void k_proj(const short* __restrict__ xt,
                                                 const short* __restrict__ Wt,
                                                 short* __restrict__ Q,
                                                 short* __restrict__ K,
                                                 short* __restrict__ VT) {
    int id = blockIdx.x;                // 768 = 4b * 32mt * 2nt * 3w
    int wsel = id % 3; id /= 3;
    int nt = id & 1;  id >>= 1;
    int mt = id & 31; int b = id >> 5;
    int t = threadIdx.x, l = t & 63, w = t >> 6;
    int lr = l & 15, lg = l >> 4;
    int wr = w >> 1, wc = w & 1;        // wave sub-tile: 64m x 64n
    __shared__ __align__(16) short Xa[128 * 64];
    __shared__ __align__(16) short Wa[128 * 64];
    const short* Xg = xt + (((size_t)b << 12) + mt * 128) * 256;
    const short* Wg = Wt + ((size_t)wsel * 256 + nt * 128) * 256;
    f32x4 acc[4][4] = {};

    #pragma unroll
    for (int ks = 0; ks < 4; ++ks) {
        stage128x64(Xg + ks * 64, Xa, t);
        stage128x64(Wg + ks * 64, Wa, t);
        __syncthreads();
        #pragma unroll
        for (int s = 0; s < 2; ++s) {
            bf16x8 af[4], bw[4];
            #pragma unroll
            for (int ms = 0; ms < 4; ++ms) {
                int row = wr * 64 + ms * 16 + lr;
                af[ms] = *(const bf16x8*)(Xa + row * 64 + (((s * 4 + lg) ^ (row & 7)) << 3));
            }
            #pragma unroll
            for (int fn = 0; fn < 4; ++fn) {
                int row = wc * 64 + fn * 16 + lr;
                bw[fn] = *(const bf16x8*)(Wa + row * 64 + (((s * 4 + lg) ^ (row & 7)) << 3));
            }
            #pragma unroll
            for (int ms = 0; ms < 4; ++ms)
                #pragma unroll
                for (int fn = 0; fn < 4; ++fn)
                    acc[ms][fn] = __builtin_amdgcn_mfma_f32_16x16x32_bf16(af[ms], bw[fn], acc[ms][fn], 0, 0, 0);
        }
        __syncthreads();
    }

    int m0 = mt * 128 + wr * 64;
    int n0 = nt * 128 + wc * 64;
    if (wsel < 2) {
        float scl = (wsel == 0) ? 0.0625f : 1.0f;
        short* dst = (wsel == 0) ? Q : K;
        #pragma unroll
        for (int ms = 0; ms < 4; ++ms)
            #pragma unroll
            for (int fn = 0; fn < 4; ++fn)
                #pragma unroll
                for (int r = 0; r < 4; ++r) {
                    int m = m0 + ms * 16 + lg * 4 + r;
                    int n = n0 + fn * 16 + lr;
                    dst[((b << 12) + m) * 256 + n] = f2bf(acc[ms][fn][r] * scl);
                }
    } else {
        #pragma unroll
        for (int ms = 0; ms < 4; ++ms)
            #pragma unroll
            for (int fn = 0; fn < 4; ++fn) {
                int n = n0 + fn * 16 + lr;
                int m = m0 + ms * 16 + lg * 4;
                bf16x4 v;
                #pragma unroll
                for (int r = 0; r < 4; ++r) v[r] = f2bf(acc[ms][fn][r]);
                *(bf16x4*)(VT + ((b * 256 + n) << 12) + m) = v;
            }
    }
}

// ---------------- k_E: round-9 structure + __launch_bounds__(256,4) (round-12/13 proven)
__global__ __launch_bounds__(256, 4) void k_E(const short* __restrict__ Qm,
                                              const short* __restrict__ Km,
                                              short* __restrict__ E,
                                              float* __restrict__ pl) {
    int o = blockIdx.x;                 // 4096
    int bid = (o & 7) * 512 + (o >> 3); // XCD swizzle (4096 % 8 == 0)
    int qt = bid & 31, kt = (bid >> 5) & 31, b = bid >> 10;
    int t = threadIdx.x, l = t & 63;
    int w = t >> 6;
    int wr = w >> 1, wc = w & 1;        // wave sub-tile: 64k x 64q
    int lr = l & 15, lg = l >> 4;
    __shared__ __align__(16) short Ka[128 * 64];
    __shared__ __align__(16) short Qa[128 * 64];
    __shared__ float plds[128];
    const short* Kg = Km + (((size_t)b << 12) + kt * 128) * 256;
    const short* Qg = Qm + (((size_t)b << 12) + qt * 128) * 256;
    f32x4 acc[4][4] = {};

    #pragma unroll
    for (int ks = 0; ks < 4; ++ks) {
        stage128x64(Kg + ks * 64, Ka, t);
        stage128x64(Qg + ks * 64, Qa, t);
        __syncthreads();
        #pragma unroll
        for (int s = 0; s < 2; ++s) {
            bf16x8 a[4], bq[4];
            #pragma unroll
            for (int mk = 0; mk < 4; ++mk) {
                int row = wr * 64 + mk * 16 + lr;
                a[mk] = *(const bf16x8*)(Ka + row * 64 + (((s * 4 + lg) ^ (row & 7)) << 3));
            }
            #pragma unroll
            for (int nq = 0; nq < 4; ++nq) {
                int row = wc * 64 + nq * 16 + lr;
                bq[nq] = *(const bf16x8*)(Qa + row * 64 + (((s * 4 + lg) ^ (row & 7)) << 3));
            }
            #pragma unroll
            for (int mk = 0; mk < 4; ++mk)
                #pragma unroll
                for (int nq = 0; nq < 4; ++nq)
                    acc[mk][nq] = __builtin_amdgcn_mfma_f32_16x16x32_bf16(a[mk], bq[nq], acc[mk][nq], 0, 0, 0);
        }
        __syncthreads();
    }

    // epilogue: e = expf(acc) (scale pre-folded into Q), RNE pack, store,
    // and column (q) partial sums
    int k0 = kt * 128 + wr * 64;
    int q0 = qt * 128 + wc * 64;
    float psum[4][4];                   // [mk][r]
    #pragma unroll
    for (int mk = 0; mk < 4; ++mk) {
        float ps0 = 0.f, ps1 = 0.f, ps2 = 0.f, ps3 = 0.f;
        #pragma unroll
        for (int nq = 0; nq < 4; ++nq) {
            int q = q0 + nq * 16 + lr;
            float e0 = __expf(acc[mk][nq][0]);
            float e1 = __expf(acc[mk][nq][1]);
            float e2 = __expf(acc[mk][nq][2]);
            float e3 = __expf(acc[mk][nq][3]);
            ps0 += e0; ps1 += e1; ps2 += e2; ps3 += e3;
            bf16x4 ev;
            ev[0] = f2bf(e0); ev[1] = f2bf(e1); ev[2] = f2bf(e2); ev[3] = f2bf(e3);
            *(bf16x4*)(E + (((size_t)b << 12) + q) * 4096 + k0 + mk * 16 + lg * 4) = ev;
        }
        psum[mk][0] = ps0; psum[mk][1] = ps1; psum[mk][2] = ps2; psum[mk][3] = ps3;
    }
    #pragma unroll
    for (int mk = 0; mk < 4; ++mk)
        #pragma unroll
        for (int r = 0; r < 4; ++r) {
            float v = psum[mk][r];
            v += __shfl_xor(v, 1);
            v += __shfl_xor(v, 2);
            v += __shfl_xor(v, 4);
            v += __shfl_xor(v, 8);
            psum[mk][r] = v;
        }
    if (wc == 0 && lr == 0) {
        #pragma unroll
        for (int mk = 0; mk < 4; ++mk)
            #pragma unroll
            for (int r = 0; r < 4; ++r)
                plds[wr * 64 + mk * 16 + lg * 4 + r] = psum[mk][r];
    }
    __syncthreads();
    if (wc == 1 && lr == 0) {
        #pragma unroll
        for (int mk = 0; mk < 4; ++mk)
            #pragma unroll
            for (int r = 0; r < 4; ++r)
                plds[wr * 64 + mk * 16 + lg * 4 + r] += psum[mk][r];
    }
    __syncthreads();
    if (t < 128) pl[(b * 32 + qt) * 4096 + kt * 128 + t] = plds[t];
}

// k_lred: rl[b][k] = 1 / sum_qt pl[b][qt][k]
__global__ void k_lred(const float* __restrict__ pl, float* __restrict__ rl) {
    int gid = blockIdx.x * 256 + threadIdx.x;   // 16384
    float s = 0.f;
    int b = gid >> 12, k = gid & 4095;
    #pragma unroll
    for (int qt = 0; qt < 32; ++qt) s += pl[(b * 32 + qt) * 4096 + k];
    rl[gid] = 1.0f / s;
}

// k_vn: Vnt[b][c][k] = VT[b][c][k] * rl[b][k]
__global__ void k_vn(const short* __restrict__ VT, const float* __restrict__ rl,
                     short* __restrict__ Vnt) {
    int gid = blockIdx.x * 256 + threadIdx.x;   // 524288
    int idx8 = gid * 8;
    int b = idx8 >> 20;
    int rem = idx8 & 1048575;
    int k = rem & 4095;
    bf16x8 v = *(const bf16x8*)(VT + idx8);
    const float* rb = rl + (b << 12) + k;
    f32x4 r0 = *(const f32x4*)(rb);
    f32x4 r1 = *(const f32x4*)(rb + 4);
    bf16x8 oo;
    #pragma unroll
    for (int e = 0; e < 8; ++e) {
        float f = bf2f(v[e]);
        float rr = (e < 4) ? r0[e] : r1[e - 4];
        oo[e] = f2bf(f * rr);
    }
    *(bf16x8*)(Vnt + idx8) = oo;
}

// ---------------- k_pv (round-13/15 form, best measured): single-buffered
// 64q x 128c block, 4 waves of 32q x 64c, 2 barriers/K-step, grid 512
// (2 blocks/CU — the concurrency that round-16 showed matters more than
// eliminating the E double-read). Pair mapping: o and o+256 share (b,qt).
__global__ __launch_bounds__(256) void k_pv(const short* __restrict__ E,
                                            const short* __restrict__ Vnt,
                                            float* __restrict__ out) {
    int o = blockIdx.x;                 // 512
    int ct = o >> 8;                    // c-half
    int r = o & 255;
    int b = r >> 6, qt = r & 63;
    int t = threadIdx.x, l = t & 63, w = t >> 6;
    int wq = w >> 1, wc = w & 1;        // wave: 32 q x 64 c
    int lr = l & 15, lg = l >> 4;
    int q0 = qt * 64, c0 = ct * 128;
    __shared__ __align__(16) short Ea[64 * 64];
    __shared__ __align__(16) short Va[128 * 64];
    const short* Eg = E + (((size_t)b << 12) + q0) * 4096;
    const short* Vg = Vnt + ((size_t)(b * 256 + c0)) * 4096;
    f32x4 acc[2][4] = {};

    for (int kc = 0; kc < 4096; kc += 64) {
        stage64x64(Eg + kc, Ea, t);
        stage128x64v(Vg + kc, Va, t);
        __syncthreads();
        bf16x8 Af[2][2], Bf[4][2];
        #pragma unroll
        for (int s = 0; s < 2; ++s) {
            #pragma unroll
            for (int mq = 0; mq < 2; ++mq) {
                int row = wq * 32 + mq * 16 + lr;
                Af[mq][s] = *(const bf16x8*)(Ea + row * 64 + (((s * 4 + lg) ^ (row & 7)) << 3));
            }
            #pragma unroll
            for (int nc = 0; nc < 4; ++nc) {
                int row = wc * 64 + nc * 16 + lr;
                Bf[nc][s] = *(const bf16x8*)(Va + row * 64 + (((s * 4 + lg) ^ (row & 7)) << 3));
            }
        }
        #pragma unroll
        for (int s = 0; s < 2; ++s)
            #pragma unroll
            for (int mq = 0; mq < 2; ++mq)
                #pragma unroll
                for (int nc = 0; nc < 4; ++nc)
                    acc[mq][nc] = __builtin_amdgcn_mfma_f32_16x16x32_bf16(Af[mq][s], Bf[nc][s], acc[mq][nc], 0, 0, 0);
        __syncthreads();
    }
    #pragma unroll
    for (int mq = 0; mq < 2; ++mq)
        #pragma unroll
        for (int nc = 0; nc < 4; ++nc) {
            int c = c0 + wc * 64 + nc * 16 + lr;
            int q = q0 + wq * 32 + mq * 16 + lg * 4;
            *(f32x4*)(out + (((size_t)b << 8) + c) * 4096 + q) = acc[mq][nc];
        }
}

extern "C" void kernel_launch(void* const* d_in, const int* in_sizes, int n_in,
                              void* d_out, int out_size, void* d_ws, size_t ws_size,
                              hipStream_t stream) {
    const float* x  = (const float*)d_in[0];
    const float* Wq = (const float*)d_in[1];
    const float* Wk = (const float*)d_in[2];
    const float* Wv = (const float*)d_in[3];

    char* p = (char*)d_ws;
    short* xt  = (short*)p; p += 4 * 4096 * 256 * 2;   // 8 MB
    short* Wt  = (short*)p; p += 3 * 256 * 256 * 2;    // 384 KB
    short* Qm  = (short*)p; p += 4 * 4096 * 256 * 2;
    short* Km  = (short*)p; p += 4 * 4096 * 256 * 2;
    short* VT  = (short*)p; p += 4 * 4096 * 256 * 2;
    short* E   = (short*)p; p += (size_t)4 * 4096 * 4096 * 2;  // 134.2 MB
    float* pl  = (float*)p; p += 4 * 32 * 4096 * 4;            // 2 MB
    float* rl  = (float*)p; p += 4 * 4096 * 4;                 // 64 KB
    short* Vnt = (short*)p; p += 4 * 4096 * 256 * 2;           // 8 MB

    float* out = (float*)d_out;

    k_prep <<<1280, 256, 0, stream>>>(x, Wq, Wk, Wv, xt, Wt);
    k_proj <<<768, 256, 0, stream>>>(xt, Wt, Qm, Km, VT);
    k_E    <<<4096, 256, 0, stream>>>(Qm, Km, E, pl);
    k_lred <<<64,   256, 0, stream>>>(pl, rl);
    k_vn   <<<2048, 256, 0, stream>>>(VT, rl, Vnt);
    k_pv   <<<512,  256, 0, stream>>>(E, Vnt, out);
}

// Round 18
// 159.564 us; speedup vs baseline: 1.1068x; 1.0306x over previous
//
#include <hip/hip_runtime.h>
#include <hip/hip_bf16.h>
#include <math.h>

typedef float f32x4 __attribute__((ext_vector_type(4)));
typedef short bf16x8 __attribute__((ext_vector_type(8)));
typedef short bf16x4 __attribute__((ext_vector_type(4)));

#define AS1 __attribute__((address_space(1)))
#define AS3 __attribute__((address_space(3)))

__device__ __forceinline__ short f2bf(float f) {
    unsigned u = __float_as_uint(f);
    unsigned r = (u + 0x7fffu + ((u >> 16) & 1u)) >> 16;
    return (short)r;
}
__device__ __forceinline__ float bf2f(short s) {
    return __uint_as_float(((unsigned)(unsigned short)s) << 16);
}
__device__ __forceinline__ void gld16(const void* g, void* l) {
    __builtin_amdgcn_global_load_lds((const AS1 unsigned int*)g, (AS3 unsigned int*)l, 16, 0, 0);
}

// stage a [128][64]-short tile (global row stride 256 shorts) into linear LDS
// with XOR-swizzled SOURCE (slot ^= row&7); reads use the matching swizzle.
// 256-thread version (4 chunks/thread).
__device__ __forceinline__ void stage128x64(const short* __restrict__ g,
                                            short* lds, int t) {
    int w = t >> 6, l = t & 63;
    #pragma unroll
    for (int j = 0; j < 4; ++j) {
        int ii = j * 4 + w;
        int row = ii * 8 + (l >> 3);
        int slot = (l & 7) ^ (row & 7);
        gld16(g + row * 256 + slot * 8, lds + ii * 512);
    }
}

// stage a [64][64]-short tile (global row stride 4096) into linear LDS,
// source pre-swizzled with slot^=(row&7) (8 slots/row of 16B).
__device__ __forceinline__ void stage64x64(const short* __restrict__ g,
                                           short* lds, int t) {
    #pragma unroll
    for (int j = 0; j < 2; ++j) {
        int idx = j * 256 + t;
        int row = idx >> 3;
        int slot = (idx & 7) ^ (row & 7);
        gld16(g + (size_t)row * 4096 + slot * 8, lds + idx * 8);
    }
}

// stage a [128][64]-short tile (global row stride 4096) into linear LDS,
// source pre-swizzled with slot^=(row&7).
__device__ __forceinline__ void stage128x64v(const short* __restrict__ g,
                                             short* lds, int t) {
    #pragma unroll
    for (int j = 0; j < 4; ++j) {
        int idx = j * 256 + t;
        int row = idx >> 3;
        int slot = (idx & 7) ^ (row & 7);
        gld16(g + (size_t)row * 4096 + slot * 8, lds + idx * 8);
    }
}

// ---------------- kernel 0+1 merged: weight transpose (bid<768) + pe/x transpose
__global__ __launch_bounds__(256) void k_prep(const float* __restrict__ x,
                                              const float* __restrict__ Wq,
                                              const float* __restrict__ Wk,
                                              const float* __restrict__ Wv,
                                              short* __restrict__ xt,
                                              short* __restrict__ Wt) {
    int bidx = blockIdx.x;              // 1280 = 768 wt + 512 pe
    if (bidx < 768) {
        int wsel = bidx >> 8, n = bidx & 255, k = threadIdx.x;
        const float* W = (wsel == 0) ? Wq : (wsel == 1) ? Wk : Wv;
        Wt[(wsel * 256 + n) * 256 + k] = f2bf(W[k * 256 + n]);
        return;
    }
    int bid = bidx - 768;               // 512 = 4 b * 128 pblocks(32)
    int b = bid >> 7;
    int pb = bid & 127;
    __shared__ __align__(16) float tile[256][33];
    __shared__ __align__(16) float pew[128][32];
    __shared__ __align__(16) float peh[128];
    int t = threadIdx.x;
    const float c1 = 0.14391156f;       // ln(10000)/64
    int wbase = (pb & 1) * 32;
    int hpos = pb >> 1;
    #pragma unroll
    for (int j = 0; j < 16; ++j) {
        int idx = t + j * 256;          // < 4096
        int c = idx >> 5, pp = idx & 31;
        int i = c >> 1;
        float d = expf(-(float)i * c1);
        float arg = (float)(wbase + pp) * d;
        pew[c][pp] = (c & 1) ? cosf(arg) : sinf(arg);
    }
    if (t < 128) {
        int i = t >> 1;
        float d = expf(-(float)i * c1);
        float arg = (float)hpos * d;
        peh[t] = (t & 1) ? cosf(arg) : sinf(arg);
    }
    int p0 = pb * 32;
    #pragma unroll
    for (int j = 0; j < 32; ++j) {
        int c = j * 8 + (t >> 5);
        int pp = t & 31;
        tile[c][pp] = x[((b * 256 + c) << 12) + p0 + pp];
    }
    __syncthreads();
    int pp = t >> 3, cseg = t & 7;
    int p = p0 + pp;
    short* dst = xt + (((b << 12) + p) << 8) + (cseg << 5);
    #pragma unroll
    for (int j = 0; j < 4; ++j) {
        bf16x8 v;
        #pragma unroll
        for (int e = 0; e < 8; ++e) {
            int c = cseg * 32 + j * 8 + e;
            float pe = (c < 128) ? pew[c][pp] : peh[c - 128];
            v[e] = f2bf(tile[c][pp] + pe);
        }
        ((bf16x8*)dst)[j] = v;
    }
}

// ---------------- kernel 2: LDS-staged projections (m97-style K-loop).
// Q = (xt@Wq)*0.0625, K = xt@Wk, V^T.
__global__ __launch_bounds__(256, 4) void k_proj(const short* __restrict__ xt,
                                                 const short* __restrict__ Wt,
                                                 short* __restrict__ Q,
                                                 short* __restrict__ K,
                                                 short* __restrict__ VT) {
    int id = blockIdx.x;                // 768 = 4b * 32mt * 2nt * 3w
    int wsel = id % 3; id /= 3;
    int nt = id & 1;  id >>= 1;
    int mt = id & 31; int b = id >> 5;
    int t = threadIdx.x, l = t & 63, w = t >> 6;
    int lr = l & 15, lg = l >> 4;
    int wr = w >> 1, wc = w & 1;        // wave sub-tile: 64m x 64n
    __shared__ __align__(16) short Xa[128 * 64];
    __shared__ __align__(16) short Wa[128 * 64];
    const short* Xg = xt + (((size_t)b << 12) + mt * 128) * 256;
    const short* Wg = Wt + ((size_t)wsel * 256 + nt * 128) * 256;
    f32x4 acc[4][4] = {};

    #pragma unroll
    for (int ks = 0; ks < 4; ++ks) {
        stage128x64(Xg + ks * 64, Xa, t);
        stage128x64(Wg + ks * 64, Wa, t);
        __syncthreads();
        #pragma unroll
        for (int s = 0; s < 2; ++s) {
            bf16x8 af[4], bw[4];
            #pragma unroll
            for (int ms = 0; ms < 4; ++ms) {
                int row = wr * 64 + ms * 16 + lr;
                af[ms] = *(const bf16x8*)(Xa + row * 64 + (((s * 4 + lg) ^ (row & 7)) << 3));
            }
            #pragma unroll
            for (int fn = 0; fn < 4; ++fn) {
                int row = wc * 64 + fn * 16 + lr;
                bw[fn] = *(const bf16x8*)(Wa + row * 64 + (((s * 4 + lg) ^ (row & 7)) << 3));
            }
            #pragma unroll
            for (int ms = 0; ms < 4; ++ms)
                #pragma unroll
                for (int fn = 0; fn < 4; ++fn)
                    acc[ms][fn] = __builtin_amdgcn_mfma_f32_16x16x32_bf16(af[ms], bw[fn], acc[ms][fn], 0, 0, 0);
        }
        __syncthreads();
    }

    int m0 = mt * 128 + wr * 64;
    int n0 = nt * 128 + wc * 64;
    if (wsel < 2) {
        float scl = (wsel == 0) ? 0.0625f : 1.0f;
        short* dst = (wsel == 0) ? Q : K;
        #pragma unroll
        for (int ms = 0; ms < 4; ++ms)
            #pragma unroll
            for (int fn = 0; fn < 4; ++fn)
                #pragma unroll
                for (int r = 0; r < 4; ++r) {
                    int m = m0 + ms * 16 + lg * 4 + r;
                    int n = n0 + fn * 16 + lr;
                    dst[((b << 12) + m) * 256 + n] = f2bf(acc[ms][fn][r] * scl);
                }
    } else {
        #pragma unroll
        for (int ms = 0; ms < 4; ++ms)
            #pragma unroll
            for (int fn = 0; fn < 4; ++fn) {
                int n = n0 + fn * 16 + lr;
                int m = m0 + ms * 16 + lg * 4;
                bf16x4 v;
                #pragma unroll
                for (int r = 0; r < 4; ++r) v[r] = f2bf(acc[ms][fn][r]);
                *(bf16x4*)(VT + ((b * 256 + n) << 12) + m) = v;
            }
    }
}

// ---------------- k_E v11: 128k x 256q tile, 512 threads (8 waves of 64x64),
// 2-barrier K-loop (barrier cost per FLOP halved vs 128x128). Staging patterns
// are the round-16-proven 512-thread forms; compute/epilogue per-thread code is
// the round-13-proven k_E with re-derived q0/k0 and a 4-way plds merge.
__global__ __launch_bounds__(512) void k_E(const short* __restrict__ Qm,
                                           const short* __restrict__ Km,
                                           short* __restrict__ E,
                                           float* __restrict__ pl) {
    int o = blockIdx.x;                 // 2048 = 4b * 32kt * 16qt
    int bid = (o & 7) * 256 + (o >> 3); // XCD swizzle (2048 % 8 == 0, bijective)
    int qt = bid & 15, kt = (bid >> 4) & 31, b = bid >> 9;
    int t = threadIdx.x, l = t & 63;
    int w = t >> 6;
    int wrk = w & 1, wcq = w >> 1;      // wave sub-tile: 64k x 64q (2 x 4 waves)
    int lr = l & 15, lg = l >> 4;
    __shared__ __align__(16) short Ka[128 * 64];   // 16 KB
    __shared__ __align__(16) short Qa[256 * 64];   // 32 KB
    __shared__ float plds[4 * 128];                // 2 KB
    const short* Kg = Km + (((size_t)b << 12) + kt * 128) * 256;
    const short* Qg = Qm + (((size_t)b << 12) + qt * 256) * 256;
    f32x4 acc[4][4] = {};

    #pragma unroll
    for (int ks = 0; ks < 4; ++ks) {
        // K tile [128][64]: 1024 chunks, 2/thread
        #pragma unroll
        for (int j = 0; j < 2; ++j) {
            int idx = j * 512 + t;
            int row = idx >> 3;
            int slot = (idx & 7) ^ (row & 7);
            gld16(Kg + ks * 64 + row * 256 + slot * 8, Ka + idx * 8);
        }
        // Q tile [256][64]: 2048 chunks, 4/thread
        #pragma unroll
        for (int j = 0; j < 4; ++j) {
            int idx = j * 512 + t;
            int row = idx >> 3;
            int slot = (idx & 7) ^ (row & 7);
            gld16(Qg + ks * 64 + row * 256 + slot * 8, Qa + idx * 8);
        }
        __syncthreads();
        #pragma unroll
        for (int s = 0; s < 2; ++s) {
            bf16x8 a[4], bq[4];
            #pragma unroll
            for (int mk = 0; mk < 4; ++mk) {
                int row = wrk * 64 + mk * 16 + lr;
                a[mk] = *(const bf16x8*)(Ka + row * 64 + (((s * 4 + lg) ^ (row & 7)) << 3));
            }
            #pragma unroll
            for (int nq = 0; nq < 4; ++nq) {
                int row = wcq * 64 + nq * 16 + lr;
                bq[nq] = *(const bf16x8*)(Qa + row * 64 + (((s * 4 + lg) ^ (row & 7)) << 3));
            }
            #pragma unroll
            for (int mk = 0; mk < 4; ++mk)
                #pragma unroll
                for (int nq = 0; nq < 4; ++nq)
                    acc[mk][nq] = __builtin_amdgcn_mfma_f32_16x16x32_bf16(a[mk], bq[nq], acc[mk][nq], 0, 0, 0);
        }
        __syncthreads();
    }

    // epilogue: e = expf(acc) (scale pre-folded into Q), RNE pack, store,
    // and column (q) partial sums
    int k0 = kt * 128 + wrk * 64;
    int q0 = qt * 256 + wcq * 64;
    float psum[4][4];                   // [mk][r]
    #pragma unroll
    for (int mk = 0; mk < 4; ++mk) {
        float ps0 = 0.f, ps1 = 0.f, ps2 = 0.f, ps3 = 0.f;
        #pragma unroll
        for (int nq = 0; nq < 4; ++nq) {
            int q = q0 + nq * 16 + lr;
            float e0 = __expf(acc[mk][nq][0]);
            float e1 = __expf(acc[mk][nq][1]);
            float e2 = __expf(acc[mk][nq][2]);
            float e3 = __expf(acc[mk][nq][3]);
            ps0 += e0; ps1 += e1; ps2 += e2; ps3 += e3;
            bf16x4 ev;
            ev[0] = f2bf(e0); ev[1] = f2bf(e1); ev[2] = f2bf(e2); ev[3] = f2bf(e3);
            *(bf16x4*)(E + (((size_t)b << 12) + q) * 4096 + k0 + mk * 16 + lg * 4) = ev;
        }
        psum[mk][0] = ps0; psum[mk][1] = ps1; psum[mk][2] = ps2; psum[mk][3] = ps3;
    }
    #pragma unroll
    for (int mk = 0; mk < 4; ++mk)
        #pragma unroll
        for (int r = 0; r < 4; ++r) {
            float v = psum[mk][r];
            v += __shfl_xor(v, 1);
            v += __shfl_xor(v, 2);
            v += __shfl_xor(v, 4);
            v += __shfl_xor(v, 8);
            psum[mk][r] = v;
        }
    // each wave (wrk,wcq) owns distinct plds[wcq][wrk*64 .. wrk*64+63]
    if (lr == 0) {
        #pragma unroll
        for (int mk = 0; mk < 4; ++mk)
            #pragma unroll
            for (int r = 0; r < 4; ++r)
                plds[wcq * 128 + wrk * 64 + mk * 16 + lg * 4 + r] = psum[mk][r];
    }
    __syncthreads();
    if (t < 128) {
        float s = plds[t] + plds[128 + t] + plds[256 + t] + plds[384 + t];
        pl[(b * 16 + qt) * 4096 + kt * 128 + t] = s;
    }
}

// k_lred: rl[b][k] = 1 / sum_qt pl[b][qt][k]   (16 q-tiles of 256)
__global__ void k_lred(const float* __restrict__ pl, float* __restrict__ rl) {
    int gid = blockIdx.x * 256 + threadIdx.x;   // 16384
    float s = 0.f;
    int b = gid >> 12, k = gid & 4095;
    #pragma unroll
    for (int qt = 0; qt < 16; ++qt) s += pl[(b * 16 + qt) * 4096 + k];
    rl[gid] = 1.0f / s;
}

// k_vn: Vnt[b][c][k] = VT[b][c][k] * rl[b][k]
__global__ void k_vn(const short* __restrict__ VT, const float* __restrict__ rl,
                     short* __restrict__ Vnt) {
    int gid = blockIdx.x * 256 + threadIdx.x;   // 524288
    int idx8 = gid * 8;
    int b = idx8 >> 20;
    int rem = idx8 & 1048575;
    int k = rem & 4095;
    bf16x8 v = *(const bf16x8*)(VT + idx8);
    const float* rb = rl + (b << 12) + k;
    f32x4 r0 = *(const f32x4*)(rb);
    f32x4 r1 = *(const f32x4*)(rb + 4);
    bf16x8 oo;
    #pragma unroll
    for (int e = 0; e < 8; ++e) {
        float f = bf2f(v[e]);
        float rr = (e < 4) ? r0[e] : r1[e - 4];
        oo[e] = f2bf(f * rr);
    }
    *(bf16x8*)(Vnt + idx8) = oo;
}

// ---------------- k_pv (round-13/15 form, best measured): single-buffered
// 64q x 128c block, 4 waves of 32q x 64c, 2 barriers/K-step, grid 512
// (2 blocks/CU). Pair mapping: o and o+256 share (b,qt).
__global__ __launch_bounds__(256) void k_pv(const short* __restrict__ E,
                                            const short* __restrict__ Vnt,
                                            float* __restrict__ out) {
    int o = blockIdx.x;                 // 512
    int ct = o >> 8;                    // c-half
    int r = o & 255;
    int b = r >> 6, qt = r & 63;
    int t = threadIdx.x, l = t & 63, w = t >> 6;
    int wq = w >> 1, wc = w & 1;        // wave: 32 q x 64 c
    int lr = l & 15, lg = l >> 4;
    int q0 = qt * 64, c0 = ct * 128;
    __shared__ __align__(16) short Ea[64 * 64];
    __shared__ __align__(16) short Va[128 * 64];
    const short* Eg = E + (((size_t)b << 12) + q0) * 4096;
    const short* Vg = Vnt + ((size_t)(b * 256 + c0)) * 4096;
    f32x4 acc[2][4] = {};

    for (int kc = 0; kc < 4096; kc += 64) {
        stage64x64(Eg + kc, Ea, t);
        stage128x64v(Vg + kc, Va, t);
        __syncthreads();
        bf16x8 Af[2][2], Bf[4][2];
        #pragma unroll
        for (int s = 0; s < 2; ++s) {
            #pragma unroll
            for (int mq = 0; mq < 2; ++mq) {
                int row = wq * 32 + mq * 16 + lr;
                Af[mq][s] = *(const bf16x8*)(Ea + row * 64 + (((s * 4 + lg) ^ (row & 7)) << 3));
            }
            #pragma unroll
            for (int nc = 0; nc < 4; ++nc) {
                int row = wc * 64 + nc * 16 + lr;
                Bf[nc][s] = *(const bf16x8*)(Va + row * 64 + (((s * 4 + lg) ^ (row & 7)) << 3));
            }
        }
        #pragma unroll
        for (int s = 0; s < 2; ++s)
            #pragma unroll
            for (int mq = 0; mq < 2; ++mq)
                #pragma unroll
                for (int nc = 0; nc < 4; ++nc)
                    acc[mq][nc] = __builtin_amdgcn_mfma_f32_16x16x32_bf16(Af[mq][s], Bf[nc][s], acc[mq][nc], 0, 0, 0);
        __syncthreads();
    }
    #pragma unroll
    for (int mq = 0; mq < 2; ++mq)
        #pragma unroll
        for (int nc = 0; nc < 4; ++nc) {
            int c = c0 + wc * 64 + nc * 16 + lr;
            int q = q0 + wq * 32 + mq * 16 + lg * 4;
            *(f32x4*)(out + (((size_t)b << 8) + c) * 4096 + q) = acc[mq][nc];
        }
}

extern "C" void kernel_launch(void* const* d_in, const int* in_sizes, int n_in,
                              void* d_out, int out_size, void* d_ws, size_t ws_size,
                              hipStream_t stream) {
    const float* x  = (const float*)d_in[0];
    const float* Wq = (const float*)d_in[1];
    const float* Wk = (const float*)d_in[2];
    const float* Wv = (const float*)d_in[3];

    char* p = (char*)d_ws;
    short* xt  = (short*)p; p += 4 * 4096 * 256 * 2;   // 8 MB
    short* Wt  = (short*)p; p += 3 * 256 * 256 * 2;    // 384 KB
    short* Qm  = (short*)p; p += 4 * 4096 * 256 * 2;
    short* Km  = (short*)p; p += 4 * 4096 * 256 * 2;
    short* VT  = (short*)p; p += 4 * 4096 * 256 * 2;
    short* E   = (short*)p; p += (size_t)4 * 4096 * 4096 * 2;  // 134.2 MB
    float* pl  = (float*)p; p += 4 * 32 * 4096 * 4;            // 2 MB (16 used)
    float* rl  = (float*)p; p += 4 * 4096 * 4;                 // 64 KB
    short* Vnt = (short*)p; p += 4 * 4096 * 256 * 2;           // 8 MB

    float* out = (float*)d_out;

    k_prep <<<1280, 256, 0, stream>>>(x, Wq, Wk, Wv, xt, Wt);
    k_proj <<<768, 256, 0, stream>>>(xt, Wt, Qm, Km, VT);
    k_E    <<<2048, 512, 0, stream>>>(Qm, Km, E, pl);
    k_lred <<<64,   256, 0, stream>>>(pl, rl);
    k_vn   <<<2048, 256, 0, stream>>>(VT, rl, Vnt);
    k_pv   <<<512,  256, 0, stream>>>(E, Vnt, out);
}

// Round 19
// 155.697 us; speedup vs baseline: 1.1343x; 1.0248x over previous
//
#include <hip/hip_runtime.h>
#include <hip/hip_bf16.h>
#include <math.h>

typedef float f32x4 __attribute__((ext_vector_type(4)));
typedef short bf16x8 __attribute__((ext_vector_type(8)));
typedef short bf16x4 __attribute__((ext_vector_type(4)));

#define AS1 __attribute__((address_space(1)))
#define AS3 __attribute__((address_space(3)))

__device__ __forceinline__ short f2bf(float f) {
    unsigned u = __float_as_uint(f);
    unsigned r = (u + 0x7fffu + ((u >> 16) & 1u)) >> 16;
    return (short)r;
}
__device__ __forceinline__ float bf2f(short s) {
    return __uint_as_float(((unsigned)(unsigned short)s) << 16);
}
__device__ __forceinline__ void gld16(const void* g, void* l) {
    __builtin_amdgcn_global_load_lds((const AS1 unsigned int*)g, (AS3 unsigned int*)l, 16, 0, 0);
}

// stage a [128][64]-short tile (global row stride 256 shorts) into linear LDS
// with XOR-swizzled SOURCE (slot ^= row&7); reads use the matching swizzle.
// 256-thread version (4 chunks/thread).
__device__ __forceinline__ void stage128x64(const short* __restrict__ g,
                                            short* lds, int t) {
    int w = t >> 6, l = t & 63;
    #pragma unroll
    for (int j = 0; j < 4; ++j) {
        int ii = j * 4 + w;
        int row = ii * 8 + (l >> 3);
        int slot = (l & 7) ^ (row & 7);
        gld16(g + row * 256 + slot * 8, lds + ii * 512);
    }
}

// ---------------- kernel 0+1 merged: weight transpose (bid<768) + pe/x transpose
__global__ __launch_bounds__(256) void k_prep(const float* __restrict__ x,
                                              const float* __restrict__ Wq,
                                              const float* __restrict__ Wk,
                                              const float* __restrict__ Wv,
                                              short* __restrict__ xt,
                                              short* __restrict__ Wt) {
    int bidx = blockIdx.x;              // 1280 = 768 wt + 512 pe
    if (bidx < 768) {
        int wsel = bidx >> 8, n = bidx & 255, k = threadIdx.x;
        const float* W = (wsel == 0) ? Wq : (wsel == 1) ? Wk : Wv;
        Wt[(wsel * 256 + n) * 256 + k] = f2bf(W[k * 256 + n]);
        return;
    }
    int bid = bidx - 768;               // 512 = 4 b * 128 pblocks(32)
    int b = bid >> 7;
    int pb = bid & 127;
    __shared__ __align__(16) float tile[256][33];
    __shared__ __align__(16) float pew[128][32];
    __shared__ __align__(16) float peh[128];
    int t = threadIdx.x;
    const float c1 = 0.14391156f;       // ln(10000)/64
    int wbase = (pb & 1) * 32;
    int hpos = pb >> 1;
    #pragma unroll
    for (int j = 0; j < 16; ++j) {
        int idx = t + j * 256;          // < 4096
        int c = idx >> 5, pp = idx & 31;
        int i = c >> 1;
        float d = expf(-(float)i * c1);
        float arg = (float)(wbase + pp) * d;
        pew[c][pp] = (c & 1) ? cosf(arg) : sinf(arg);
    }
    if (t < 128) {
        int i = t >> 1;
        float d = expf(-(float)i * c1);
        float arg = (float)hpos * d;
        peh[t] = (t & 1) ? cosf(arg) : sinf(arg);
    }
    int p0 = pb * 32;
    #pragma unroll
    for (int j = 0; j < 32; ++j) {
        int c = j * 8 + (t >> 5);
        int pp = t & 31;
        tile[c][pp] = x[((b * 256 + c) << 12) + p0 + pp];
    }
    __syncthreads();
    int pp = t >> 3, cseg = t & 7;
    int p = p0 + pp;
    short* dst = xt + (((b << 12) + p) << 8) + (cseg << 5);
    #pragma unroll
    for (int j = 0; j < 4; ++j) {
        bf16x8 v;
        #pragma unroll
        for (int e = 0; e < 8; ++e) {
            int c = cseg * 32 + j * 8 + e;
            float pe = (c < 128) ? pew[c][pp] : peh[c - 128];
            v[e] = f2bf(tile[c][pp] + pe);
        }
        ((bf16x8*)dst)[j] = v;
    }
}

// ---------------- kernel 2: LDS-staged projections (m97-style K-loop).
// Q = (xt@Wq)*0.0625, K = xt@Wk, V^T.
__global__ __launch_bounds__(256, 4) void k_proj(const short* __restrict__ xt,
                                                 const short* __restrict__ Wt,
                                                 short* __restrict__ Q,
                                                 short* __restrict__ K,
                                                 short* __restrict__ VT) {
    int id = blockIdx.x;                // 768 = 4b * 32mt * 2nt * 3w
    int wsel = id % 3; id /= 3;
    int nt = id & 1;  id >>= 1;
    int mt = id & 31; int b = id >> 5;
    int t = threadIdx.x, l = t & 63, w = t >> 6;
    int lr = l & 15, lg = l >> 4;
    int wr = w >> 1, wc = w & 1;        // wave sub-tile: 64m x 64n
    __shared__ __align__(16) short Xa[128 * 64];
    __shared__ __align__(16) short Wa[128 * 64];
    const short* Xg = xt + (((size_t)b << 12) + mt * 128) * 256;
    const short* Wg = Wt + ((size_t)wsel * 256 + nt * 128) * 256;
    f32x4 acc[4][4] = {};

    #pragma unroll
    for (int ks = 0; ks < 4; ++ks) {
        stage128x64(Xg + ks * 64, Xa, t);
        stage128x64(Wg + ks * 64, Wa, t);
        __syncthreads();
        #pragma unroll
        for (int s = 0; s < 2; ++s) {
            bf16x8 af[4], bw[4];
            #pragma unroll
            for (int ms = 0; ms < 4; ++ms) {
                int row = wr * 64 + ms * 16 + lr;
                af[ms] = *(const bf16x8*)(Xa + row * 64 + (((s * 4 + lg) ^ (row & 7)) << 3));
            }
            #pragma unroll
            for (int fn = 0; fn < 4; ++fn) {
                int row = wc * 64 + fn * 16 + lr;
                bw[fn] = *(const bf16x8*)(Wa + row * 64 + (((s * 4 + lg) ^ (row & 7)) << 3));
            }
            #pragma unroll
            for (int ms = 0; ms < 4; ++ms)
                #pragma unroll
                for (int fn = 0; fn < 4; ++fn)
                    acc[ms][fn] = __builtin_amdgcn_mfma_f32_16x16x32_bf16(af[ms], bw[fn], acc[ms][fn], 0, 0, 0);
        }
        __syncthreads();
    }

    int m0 = mt * 128 + wr * 64;
    int n0 = nt * 128 + wc * 64;
    if (wsel < 2) {
        float scl = (wsel == 0) ? 0.0625f : 1.0f;
        short* dst = (wsel == 0) ? Q : K;
        #pragma unroll
        for (int ms = 0; ms < 4; ++ms)
            #pragma unroll
            for (int fn = 0; fn < 4; ++fn)
                #pragma unroll
                for (int r = 0; r < 4; ++r) {
                    int m = m0 + ms * 16 + lg * 4 + r;
                    int n = n0 + fn * 16 + lr;
                    dst[((b << 12) + m) * 256 + n] = f2bf(acc[ms][fn][r] * scl);
                }
    } else {
        #pragma unroll
        for (int ms = 0; ms < 4; ++ms)
            #pragma unroll
            for (int fn = 0; fn < 4; ++fn) {
                int n = n0 + fn * 16 + lr;
                int m = m0 + ms * 16 + lg * 4;
                bf16x4 v;
                #pragma unroll
                for (int r = 0; r < 4; ++r) v[r] = f2bf(acc[ms][fn][r]);
                *(bf16x4*)(VT + ((b * 256 + n) << 12) + m) = v;
            }
    }
}

// ---------------- k_E v11 (round-18 proven): 128k x 256q tile, 512 threads
// (8 waves of 64x64), 2-barrier K-loop.
__global__ __launch_bounds__(512) void k_E(const short* __restrict__ Qm,
                                           const short* __restrict__ Km,
                                           short* __restrict__ E,
                                           float* __restrict__ pl) {
    int o = blockIdx.x;                 // 2048 = 4b * 32kt * 16qt
    int bid = (o & 7) * 256 + (o >> 3); // XCD swizzle (2048 % 8 == 0, bijective)
    int qt = bid & 15, kt = (bid >> 4) & 31, b = bid >> 9;
    int t = threadIdx.x, l = t & 63;
    int w = t >> 6;
    int wrk = w & 1, wcq = w >> 1;      // wave sub-tile: 64k x 64q (2 x 4 waves)
    int lr = l & 15, lg = l >> 4;
    __shared__ __align__(16) short Ka[128 * 64];   // 16 KB
    __shared__ __align__(16) short Qa[256 * 64];   // 32 KB
    __shared__ float plds[4 * 128];                // 2 KB
    const short* Kg = Km + (((size_t)b << 12) + kt * 128) * 256;
    const short* Qg = Qm + (((size_t)b << 12) + qt * 256) * 256;
    f32x4 acc[4][4] = {};

    #pragma unroll
    for (int ks = 0; ks < 4; ++ks) {
        #pragma unroll
        for (int j = 0; j < 2; ++j) {
            int idx = j * 512 + t;
            int row = idx >> 3;
            int slot = (idx & 7) ^ (row & 7);
            gld16(Kg + ks * 64 + row * 256 + slot * 8, Ka + idx * 8);
        }
        #pragma unroll
        for (int j = 0; j < 4; ++j) {
            int idx = j * 512 + t;
            int row = idx >> 3;
            int slot = (idx & 7) ^ (row & 7);
            gld16(Qg + ks * 64 + row * 256 + slot * 8, Qa + idx * 8);
        }
        __syncthreads();
        #pragma unroll
        for (int s = 0; s < 2; ++s) {
            bf16x8 a[4], bq[4];
            #pragma unroll
            for (int mk = 0; mk < 4; ++mk) {
                int row = wrk * 64 + mk * 16 + lr;
                a[mk] = *(const bf16x8*)(Ka + row * 64 + (((s * 4 + lg) ^ (row & 7)) << 3));
            }
            #pragma unroll
            for (int nq = 0; nq < 4; ++nq) {
                int row = wcq * 64 + nq * 16 + lr;
                bq[nq] = *(const bf16x8*)(Qa + row * 64 + (((s * 4 + lg) ^ (row & 7)) << 3));
            }
            #pragma unroll
            for (int mk = 0; mk < 4; ++mk)
                #pragma unroll
                for (int nq = 0; nq < 4; ++nq)
                    acc[mk][nq] = __builtin_amdgcn_mfma_f32_16x16x32_bf16(a[mk], bq[nq], acc[mk][nq], 0, 0, 0);
        }
        __syncthreads();
    }

    int k0 = kt * 128 + wrk * 64;
    int q0 = qt * 256 + wcq * 64;
    float psum[4][4];                   // [mk][r]
    #pragma unroll
    for (int mk = 0; mk < 4; ++mk) {
        float ps0 = 0.f, ps1 = 0.f, ps2 = 0.f, ps3 = 0.f;
        #pragma unroll
        for (int nq = 0; nq < 4; ++nq) {
            int q = q0 + nq * 16 + lr;
            float e0 = __expf(acc[mk][nq][0]);
            float e1 = __expf(acc[mk][nq][1]);
            float e2 = __expf(acc[mk][nq][2]);
            float e3 = __expf(acc[mk][nq][3]);
            ps0 += e0; ps1 += e1; ps2 += e2; ps3 += e3;
            bf16x4 ev;
            ev[0] = f2bf(e0); ev[1] = f2bf(e1); ev[2] = f2bf(e2); ev[3] = f2bf(e3);
            *(bf16x4*)(E + (((size_t)b << 12) + q) * 4096 + k0 + mk * 16 + lg * 4) = ev;
        }
        psum[mk][0] = ps0; psum[mk][1] = ps1; psum[mk][2] = ps2; psum[mk][3] = ps3;
    }
    #pragma unroll
    for (int mk = 0; mk < 4; ++mk)
        #pragma unroll
        for (int r = 0; r < 4; ++r) {
            float v = psum[mk][r];
            v += __shfl_xor(v, 1);
            v += __shfl_xor(v, 2);
            v += __shfl_xor(v, 4);
            v += __shfl_xor(v, 8);
            psum[mk][r] = v;
        }
    if (lr == 0) {
        #pragma unroll
        for (int mk = 0; mk < 4; ++mk)
            #pragma unroll
            for (int r = 0; r < 4; ++r)
                plds[wcq * 128 + wrk * 64 + mk * 16 + lg * 4 + r] = psum[mk][r];
    }
    __syncthreads();
    if (t < 128) {
        float s = plds[t] + plds[128 + t] + plds[256 + t] + plds[384 + t];
        pl[(b * 16 + qt) * 4096 + kt * 128 + t] = s;
    }
}

// k_lred: rl[b][k] = 1 / sum_qt pl[b][qt][k]   (16 q-tiles of 256)
__global__ void k_lred(const float* __restrict__ pl, float* __restrict__ rl) {
    int gid = blockIdx.x * 256 + threadIdx.x;   // 16384
    float s = 0.f;
    int b = gid >> 12, k = gid & 4095;
    #pragma unroll
    for (int qt = 0; qt < 16; ++qt) s += pl[(b * 16 + qt) * 4096 + k];
    rl[gid] = 1.0f / s;
}

// k_vn: Vnt[b][c][k] = VT[b][c][k] * rl[b][k]
__global__ void k_vn(const short* __restrict__ VT, const float* __restrict__ rl,
                     short* __restrict__ Vnt) {
    int gid = blockIdx.x * 256 + threadIdx.x;   // 524288
    int idx8 = gid * 8;
    int b = idx8 >> 20;
    int rem = idx8 & 1048575;
    int k = rem & 4095;
    bf16x8 v = *(const bf16x8*)(VT + idx8);
    const float* rb = rl + (b << 12) + k;
    f32x4 r0 = *(const f32x4*)(rb);
    f32x4 r1 = *(const f32x4*)(rb + 4);
    bf16x8 oo;
    #pragma unroll
    for (int e = 0; e < 8; ++e) {
        float f = bf2f(v[e]);
        float rr = (e < 4) ? r0[e] : r1[e - 4];
        oo[e] = f2bf(f * rr);
    }
    *(bf16x8*)(Vnt + idx8) = oo;
}

// ---------------- k_pv v9: BK=128 (halves barrier count: 32 K-steps, 2 barriers
// each vs 64x2). 64q x 128c block, 4 waves of 32q x 64c. 16-slot-row swizzle:
// stage slot=(idx&15)^(row&15), read slot=(s*4+lg)^(row&15) — 16 rows hit 16
// distinct slots, 2-way bank alias (free). LDS 48 KB (grid 512 caps at 2
// blocks/CU anyway; 160/48=3 >= 2, no occupancy loss). Pair mapping kept.
__global__ __launch_bounds__(256) void k_pv(const short* __restrict__ E,
                                            const short* __restrict__ Vnt,
                                            float* __restrict__ out) {
    int o = blockIdx.x;                 // 512
    int ct = o >> 8;                    // c-half
    int r = o & 255;
    int b = r >> 6, qt = r & 63;
    int t = threadIdx.x, l = t & 63, w = t >> 6;
    int wq = w >> 1, wc = w & 1;        // wave: 32 q x 64 c
    int lr = l & 15, lg = l >> 4;
    int q0 = qt * 64, c0 = ct * 128;
    __shared__ __align__(16) short Ea[64 * 128];   // 16 KB
    __shared__ __align__(16) short Va[128 * 128];  // 32 KB
    const short* Eg = E + (((size_t)b << 12) + q0) * 4096;
    const short* Vg = Vnt + ((size_t)(b * 256 + c0)) * 4096;
    f32x4 acc[2][4] = {};

    for (int kc = 0; kc < 4096; kc += 128) {
        // E tile [64][128]: 1024 chunks, 4/thread
        #pragma unroll
        for (int j = 0; j < 4; ++j) {
            int idx = j * 256 + t;
            int row = idx >> 4;
            int slot = (idx & 15) ^ (row & 15);
            gld16(Eg + kc + (size_t)row * 4096 + slot * 8, Ea + idx * 8);
        }
        // V tile [128][128]: 2048 chunks, 8/thread
        #pragma unroll
        for (int j = 0; j < 8; ++j) {
            int idx = j * 256 + t;
            int row = idx >> 4;
            int slot = (idx & 15) ^ (row & 15);
            gld16(Vg + kc + (size_t)row * 4096 + slot * 8, Va + idx * 8);
        }
        __syncthreads();
        #pragma unroll
        for (int s = 0; s < 4; ++s) {
            bf16x8 Af[2], Bf[4];
            #pragma unroll
            for (int mq = 0; mq < 2; ++mq) {
                int row = wq * 32 + mq * 16 + lr;
                Af[mq] = *(const bf16x8*)(Ea + row * 128 + (((s * 4 + lg) ^ (row & 15)) << 3));
            }
            #pragma unroll
            for (int nc = 0; nc < 4; ++nc) {
                int row = wc * 64 + nc * 16 + lr;
                Bf[nc] = *(const bf16x8*)(Va + row * 128 + (((s * 4 + lg) ^ (row & 15)) << 3));
            }
            #pragma unroll
            for (int mq = 0; mq < 2; ++mq)
                #pragma unroll
                for (int nc = 0; nc < 4; ++nc)
                    acc[mq][nc] = __builtin_amdgcn_mfma_f32_16x16x32_bf16(Af[mq], Bf[nc], acc[mq][nc], 0, 0, 0);
        }
        __syncthreads();
    }
    #pragma unroll
    for (int mq = 0; mq < 2; ++mq)
        #pragma unroll
        for (int nc = 0; nc < 4; ++nc) {
            int c = c0 + wc * 64 + nc * 16 + lr;
            int q = q0 + wq * 32 + mq * 16 + lg * 4;
            *(f32x4*)(out + (((size_t)b << 8) + c) * 4096 + q) = acc[mq][nc];
        }
}

extern "C" void kernel_launch(void* const* d_in, const int* in_sizes, int n_in,
                              void* d_out, int out_size, void* d_ws, size_t ws_size,
                              hipStream_t stream) {
    const float* x  = (const float*)d_in[0];
    const float* Wq = (const float*)d_in[1];
    const float* Wk = (const float*)d_in[2];
    const float* Wv = (const float*)d_in[3];

    char* p = (char*)d_ws;
    short* xt  = (short*)p; p += 4 * 4096 * 256 * 2;   // 8 MB
    short* Wt  = (short*)p; p += 3 * 256 * 256 * 2;    // 384 KB
    short* Qm  = (short*)p; p += 4 * 4096 * 256 * 2;
    short* Km  = (short*)p; p += 4 * 4096 * 256 * 2;
    short* VT  = (short*)p; p += 4 * 4096 * 256 * 2;
    short* E   = (short*)p; p += (size_t)4 * 4096 * 4096 * 2;  // 134.2 MB
    float* pl  = (float*)p; p += 4 * 32 * 4096 * 4;            // 2 MB (16 used)
    float* rl  = (float*)p; p += 4 * 4096 * 4;                 // 64 KB
    short* Vnt = (short*)p; p += 4 * 4096 * 256 * 2;           // 8 MB

    float* out = (float*)d_out;

    k_prep <<<1280, 256, 0, stream>>>(x, Wq, Wk, Wv, xt, Wt);
    k_proj <<<768, 256, 0, stream>>>(xt, Wt, Qm, Km, VT);
    k_E    <<<2048, 512, 0, stream>>>(Qm, Km, E, pl);
    k_lred <<<64,   256, 0, stream>>>(pl, rl);
    k_vn   <<<2048, 256, 0, stream>>>(VT, rl, Vnt);
    k_pv   <<<512,  256, 0, stream>>>(E, Vnt, out);
}